// Round 15
// baseline (75.689 us; speedup 1.0000x reference)
//
#include <hip/hip_runtime.h>
#include <stdint.h>

typedef float f32x4 __attribute__((ext_vector_type(4)));
typedef short s16x8 __attribute__((ext_vector_type(8)));
typedef unsigned short us4 __attribute__((ext_vector_type(4)));

#define NPTS 4096
#define DDIM 512
#define NF   24
#define NBLK 32
#define NBD  1024   // histogram bins

// ---------------- ws layout ----------------
// Eb @0 (4MB) | sq | mm(+cnt) | acc32/deg | D2h @4,603,968 (33.5MB)
#define OFF_SQ  4194304
#define OFF_MM  4210688
#define OFF_DEG 4210752
#define OFF_D   4603968
#define WS_A    54935616ULL

typedef __attribute__((address_space(1))) void gvoid;
typedef __attribute__((address_space(3))) void svoid;
#define GLD16(gp, lp) __builtin_amdgcn_global_load_lds((gvoid*)(gp), (svoid*)(lp), 16, 0, 0)

static __device__ __forceinline__ ushort f2h(float x) {
    _Float16 h = (_Float16)x;
    return __builtin_bit_cast(unsigned short, h);
}
static __device__ __forceinline__ float h2f(ushort u) {
    return (float)__builtin_bit_cast(_Float16, u);
}

// ---------------- init (path B only) ----------------
__global__ __launch_bounds__(256) void k_init(float* __restrict__ deg,
                                              unsigned* __restrict__ mm) {
    int i = blockIdx.x * 256 + threadIdx.x;
    if (i < NPTS * NF) deg[i] = 0.0f;
    if (i == 0) { mm[0] = 0x7F7FFFFFu; mm[1] = 0u; }
}

// ------- convert f32 -> bf16 (RNE), rowwise sum of squares; + tiny init ----
__global__ __launch_bounds__(256) void k_convert(const float* __restrict__ in,
                                                 ushort* __restrict__ Eb,
                                                 float* __restrict__ sq,
                                                 float* __restrict__ acc32,
                                                 unsigned* __restrict__ mm) {
    if (blockIdx.x == 0) {
        if (threadIdx.x < 32) acc32[threadIdx.x] = 0.0f;
        else if (threadIdx.x == 32) mm[0] = 0x7F7FFFFFu;
        else if (threadIdx.x == 33) mm[1] = 0u;
        else if (threadIdx.x == 34) mm[2] = 0u;   // last-block ticket counter
    }
    const int w = threadIdx.x >> 6, lane = threadIdx.x & 63;
    const int row = blockIdx.x * 4 + w;
    const float* src = in + (size_t)row * DDIM + lane * 8;
    float4 a = ((const float4*)src)[0];
    float4 b = ((const float4*)src)[1];
    float v[8] = {a.x, a.y, a.z, a.w, b.x, b.y, b.z, b.w};
    unsigned u[8];
    float ss = 0.0f;
#pragma unroll
    for (int i = 0; i < 8; ++i) {
        ss += v[i] * v[i];
        unsigned bits = __float_as_uint(v[i]);
        u[i] = (bits + 0x7FFFu + ((bits >> 16) & 1u)) >> 16;  // RNE to bf16
    }
    uint4 pk;
    pk.x = u[0] | (u[1] << 16);
    pk.y = u[2] | (u[3] << 16);
    pk.z = u[4] | (u[5] << 16);
    pk.w = u[6] | (u[7] << 16);
    *(uint4*)(Eb + (size_t)row * DDIM + lane * 8) = pk;
#pragma unroll
    for (int s = 1; s < 64; s <<= 1) ss += __shfl_xor(ss, s);
    if (lane == 0) sq[row] = ss;
}

// ============================ PATH A ======================================
// UPPER-TRI 128x128 tiles (528 blocks, XCD-swizzled). BK=64, one barrier per
// K-step, dbuf global_load_lds staging, 8-slot chunk-XOR swizzle both-sides.
// (round-11 measured-best gram; unchanged)
__global__ __launch_bounds__(256) void k_gram_bk64(const ushort* __restrict__ Eb,
                                                   const float* __restrict__ sq,
                                                   unsigned* __restrict__ mm,
                                                   ushort* __restrict__ D2h) {
    __shared__ __align__(16) ushort SM[32768];
    __shared__ float sqr[128], sqc[128], red[8];
    char* SMb = (char*)SM;
    const int tid = threadIdx.x;
    const int w = tid >> 6, lane = tid & 63, g = lane >> 4, l15 = lane & 15;
    const int wr = w >> 1, wc = w & 1;

    int bid = (blockIdx.x & 7) * 66 + (blockIdx.x >> 3);
    int rb = 0, pre = 0;
    while (pre + (NBLK - rb) <= bid) { pre += NBLK - rb; ++rb; }
    const int cb = rb + (bid - pre);

    if (tid < 128) sqr[tid] = sq[rb * 128 + tid];
    else           sqc[tid - 128] = sq[cb * 128 + (tid - 128)];

    f32x4 acc[4][4];
#pragma unroll
    for (int i = 0; i < 4; ++i)
#pragma unroll
        for (int j = 0; j < 4; ++j) acc[i][j] = (f32x4){0.f, 0.f, 0.f, 0.f};

    const int srow_off = lane >> 3, slch = lane & 7;

#define STAGE64(buf, kk)                                                        \
    {                                                                           \
        const int k0_ = (kk) * 64;                                              \
        _Pragma("unroll")                                                       \
        for (int i_ = 0; i_ < 4; ++i_) {                                        \
            const int r_  = w * 32 + i_ * 8 + srow_off;                         \
            const int ch_ = slch ^ (r_ & 7);                                    \
            GLD16(Eb + (size_t)(rb * 128 + r_) * DDIM + k0_ + ch_ * 8,          \
                  SMb + (buf) * 16384 + (w * 32 + i_ * 8) * 128);               \
            GLD16(Eb + (size_t)(cb * 128 + r_) * DDIM + k0_ + ch_ * 8,          \
                  SMb + 32768 + (buf) * 16384 + (w * 32 + i_ * 8) * 128);       \
        }                                                                       \
    }

    STAGE64(0, 0);
    int cur = 0;
#pragma unroll 1
    for (int kk = 0; kk < 8; ++kk) {
        __syncthreads();
        if (kk < 7) STAGE64(cur ^ 1, kk + 1);
        const char* Ac = SMb + cur * 16384;
        const char* Bc = SMb + 32768 + cur * 16384;
#pragma unroll
        for (int ks = 0; ks < 2; ++ks) {
            s16x8 rf[4], cf[4];
#pragma unroll
            for (int i = 0; i < 4; ++i) {
                const int r = wr * 64 + i * 16 + l15;
                const int slot = (ks * 4 + g) ^ (r & 7);
                rf[i] = *(const s16x8*)(Ac + r * 128 + slot * 16);
            }
#pragma unroll
            for (int j = 0; j < 4; ++j) {
                const int r = wc * 64 + j * 16 + l15;
                const int slot = (ks * 4 + g) ^ (r & 7);
                cf[j] = *(const s16x8*)(Bc + r * 128 + slot * 16);
            }
#pragma unroll
            for (int i = 0; i < 4; ++i)
#pragma unroll
                for (int j = 0; j < 4; ++j)
                    acc[i][j] = __builtin_amdgcn_mfma_f32_16x16x32_bf16(
                        cf[j], rf[i], acc[i][j], 0, 0, 0);
        }
        cur ^= 1;
    }
    __syncthreads();

    ushort* T = SM;
    float mn = 3.4e38f, mx = 0.0f;
#pragma unroll
    for (int i = 0; i < 4; ++i) {
        const int lr = wr * 64 + i * 16 + l15;
        const int trow = rb * 128 + lr;
        const float srv = sqr[lr];
#pragma unroll
        for (int j = 0; j < 4; ++j) {
            const int c0 = wc * 64 + j * 16 + g * 4;
            const int tc0 = cb * 128 + c0;
            ushort h[4];
#pragma unroll
            for (int m = 0; m < 4; ++m) {
                float d2 = srv + sqc[c0 + m] - 2.0f * acc[i][j][m];
                d2 = fmaxf(d2, 0.0f);
                bool diag = (tc0 + m == trow);
                mn = diag ? mn : fminf(mn, d2);
                mx = diag ? mx : fmaxf(mx, d2);
                h[m] = f2h(diag ? 6.0e4f : d2);   // diag -> huge d2 -> sigma == 0
            }
            us4 pk4 = {h[0], h[1], h[2], h[3]};
            *(us4*)(T + lr * 136 + c0) = pk4;
        }
    }
#pragma unroll
    for (int s = 1; s < 64; s <<= 1) {
        mn = fminf(mn, __shfl_xor(mn, s));
        mx = fmaxf(mx, __shfl_xor(mx, s));
    }
    if (lane == 0) { red[w] = mn; red[4 + w] = mx; }
    __syncthreads();
    if (tid == 0) {
        mn = fminf(fminf(red[0], red[1]), fminf(red[2], red[3]));
        mx = fmaxf(fmaxf(red[4], red[5]), fmaxf(red[6], red[7]));
        atomicMin(&mm[0], __float_as_uint(mn));
        atomicMax(&mm[1], __float_as_uint(mx));
    }
#pragma unroll
    for (int j = 0; j < 8; ++j) {
        const int c = j * 256 + tid;
        const int row = c >> 4, col8 = (c & 15) * 8;
        uint4 v = *(const uint4*)(T + row * 136 + col8);
        *(uint4*)(D2h + (size_t)(rb * 128 + row) * NPTS + cb * 128 + col8) = v;
    }
    if (rb != cb) {
        __syncthreads();
#pragma unroll
        for (int i = 0; i < 4; ++i) {
            const int lr = wr * 64 + i * 16 + l15;
            const float srv = sqr[lr];
#pragma unroll
            for (int j = 0; j < 4; ++j) {
                const int c0 = wc * 64 + j * 16 + g * 4;
#pragma unroll
                for (int m = 0; m < 4; ++m) {
                    float d2 = srv + sqc[c0 + m] - 2.0f * acc[i][j][m];
                    d2 = fmaxf(d2, 0.0f);
                    T[(c0 + m) * 136 + lr] = f2h(d2);
                }
            }
        }
        __syncthreads();
#pragma unroll
        for (int j2 = 0; j2 < 8; ++j2) {
            const int c = j2 * 256 + tid;
            const int row = c >> 4, col8 = (c & 15) * 8;
            uint4 v = *(const uint4*)(T + row * 136 + col8);
            *(uint4*)(D2h + (size_t)(cb * 128 + row) * NPTS + rb * 128 + col8) = v;
        }
    }
}

// FUSED hist+dot+finalize: 512 blocks x 512 threads, 8 rows/block.
// Phase 1 = hist4 structure (one wave per row, u32 LDS hist, NBD bins).
// Phase 2 = k_dot structure (f32 Wl, 6 phases, recurrence W-gen), hv read
// straight from hist LDS (no global H). Block finalize -> acc32 atomics;
// LAST block (ticket in mm[2]) computes the scalar output.
__global__ __launch_bounds__(512) void k_hd(const ushort* __restrict__ D2h,
                                            const unsigned* __restrict__ mm_,
                                            float* __restrict__ acc32,
                                            float* __restrict__ out) {
    __shared__ unsigned Hs[8][NBD + 4];   // 32,896B
    __shared__ float Wl[4][NBD];          // 16,384B
    __shared__ float degb[8][NF];
    unsigned* mm = (unsigned*)mm_;
    const int tid = threadIdx.x, w = tid >> 6, lane = tid & 63;
    const int row = blockIdx.x * 8 + w;

    for (int i = tid; i < 8 * (NBD + 4); i += 512) ((unsigned*)Hs)[i] = 0u;
    const float d2min = __uint_as_float(mm[0]);
    const float d2max = __uint_as_float(mm[1]);
    const float sc = (float)NBD / fmaxf(d2max - d2min, 1e-6f);
    __syncthreads();

    // ---- hist: wave w bins its row ----
    const uint4* Dv = (const uint4*)(D2h + (size_t)row * NPTS);
    unsigned* hr = Hs[w];
#pragma unroll
    for (int it = 0; it < 8; ++it) {
        uint4 pk = Dv[it * 64 + lane];
        unsigned pw[4] = {pk.x, pk.y, pk.z, pk.w};
#pragma unroll
        for (int i = 0; i < 4; ++i) {
            float a = h2f((ushort)(pw[i] & 0xFFFFu));
            float b = h2f((ushort)(pw[i] >> 16));
            if (a < 3.0e4f) {   // excludes the diagonal marker (6e4)
                int ba = (int)fminf(fmaxf((a - d2min) * sc, 0.0f), (float)(NBD - 1));
                atomicAdd(&hr[ba], 1u);
            }
            if (b < 3.0e4f) {
                int bb = (int)fminf(fmaxf((b - d2min) * sc, 0.0f), (float)(NBD - 1));
                atomicAdd(&hr[bb], 1u);
            }
        }
    }
    __syncthreads();

    // ---- hv from LDS hist: lane owns bins j*256 + lane*4 (j = 0..3) ----
    float hv[16];
#pragma unroll
    for (int j = 0; j < 4; ++j) {
        const unsigned* q = &Hs[w][j * 256 + lane * 4];
        hv[j * 4 + 0] = (float)q[0];
        hv[j * 4 + 1] = (float)q[1];
        hv[j * 4 + 2] = (float)q[2];
        hv[j * 4 + 3] = (float)q[3];
    }

    // ---- dot (k_dot structure, unchanged math) ----
    const float bw    = fmaxf(d2max - d2min, 1e-6f) / (float)NBD;
    const float d_min = d2min > 1e-12f ? sqrtf(d2min) : 0.0f;
    const float d_mx  = d2max > 1e-12f ? sqrtf(d2max) : 0.0f;
    const float d_max = fmaxf(d_mx, d_min + 1e-4f);
    const float stp   = (d_max - d_min) / 23.0f;
    const float S2L   = (1.0f / 0.15f) * 1.44269504f;
    const float Ds2   = stp * S2L;
    const float R     = exp2f(-Ds2);
    const float LIM   = 1073741824.0f;

    float e2[2];
#pragma unroll
    for (int q = 0; q < 2; ++q) {
        const int b = tid * 2 + q;
        const float d2c = d2min + ((float)b + 0.5f) * bw;
        const float db = sqrtf(fmaxf(d2c, 0.0f));
        e2[q] = exp2f(fminf((db - d_min) * S2L, 125.0f));
    }

#pragma unroll 1
    for (int ph = 0; ph < 6; ++ph) {
        __syncthreads();   // previous phase's readers done before overwrite
#pragma unroll
        for (int k = 0; k < 4; ++k) {
            float2 sg;
            sg.x = __builtin_amdgcn_rcpf(1.0f + fminf(e2[0], LIM)); e2[0] *= R;
            sg.y = __builtin_amdgcn_rcpf(1.0f + fminf(e2[1], LIM)); e2[1] *= R;
            *(float2*)(&Wl[k][tid * 2]) = sg;
        }
        __syncthreads();
        float dacc[4];
#pragma unroll
        for (int k = 0; k < 4; ++k) {
            const float* Wr = &Wl[k][0];
            float s = 0.0f;
#pragma unroll
            for (int j = 0; j < 4; ++j) {
                const f32x4 wv = *(const f32x4*)(Wr + j * 256 + lane * 4);
                s += hv[j*4+0]*wv[0] + hv[j*4+1]*wv[1] + hv[j*4+2]*wv[2] + hv[j*4+3]*wv[3];
            }
            dacc[k] = s;
        }
#pragma unroll
        for (int k = 0; k < 4; ++k)
#pragma unroll
            for (int o = 1; o < 64; o <<= 1) dacc[k] += __shfl_xor(dacc[k], o);
        if (lane == 0) {
#pragma unroll
            for (int k = 0; k < 4; ++k) degb[w][ph * 4 + k] = dacc[k];
        }
    }
    __syncthreads();
    if (tid < NF) {            // edge sums
        float s = 0.0f;
#pragma unroll
        for (int r = 0; r < 8; ++r) s += degb[r][tid];
        atomicAdd(&acc32[tid], s);
    } else if (tid < 32) {     // isolated counts over thresholds 16..23
        const int k = 16 + (tid - NF);
        float c = 0.0f;
#pragma unroll
        for (int r = 0; r < 8; ++r) c += (degb[r][k] < 0.5f) ? 1.0f : 0.0f;
        atomicAdd(&acc32[tid], c);
    }
    // ---- last-block finalize ----
    __syncthreads();           // block's atomics issued
    if (tid == 0) {
        __threadfence();       // publish acc32 adds
        unsigned old = atomicAdd(&mm[2], 1u);
        if (old == gridDim.x - 1) {   // all other blocks' adds are visible
            __threadfence();
            volatile float* a = (volatile float*)acc32;
            float h1 = 0.0f;
#pragma unroll
            for (int k = 0; k < NF; ++k)
                h1 += fmaxf(a[k] * 0.5f - (float)(NPTS - 1), 0.0f) * (1.0f / (float)NPTS);
            float h0 = 0.0f;
#pragma unroll
            for (int k = 0; k < 8; ++k) h0 += a[NF + k];
            out[0] = (h0 * 0.125f + 0.5f * (h1 * (1.0f / 24.0f))) * 0.1f;
        }
    }
}

// ============================ PATH B (small ws, verified) ==================
__device__ __forceinline__ void gram_tile(const ushort* __restrict__ Eb, int rb, int cb,
                                          ushort* As, ushort* Bs, f32x4 acc[2][8]) {
    const int tid = threadIdx.x;
    const int w = tid >> 6, lane = tid & 63, g = lane >> 4, l15 = lane & 15;
#pragma unroll 1
    for (int kk = 0; kk < DDIM / 32; ++kk) {
        const int k0 = kk * 32;
        __syncthreads();
#pragma unroll
        for (int it = 0; it < 2; ++it) {
            int li  = it * 256 + tid;
            int row = li >> 2, ch = li & 3;
            uint4 va = *(const uint4*)(Eb + (size_t)(rb * 128 + row) * DDIM + k0 + ch * 8);
            uint4 vb = *(const uint4*)(Eb + (size_t)(cb * 128 + row) * DDIM + k0 + ch * 8);
            *(uint4*)(As + row * 32 + ch * 8) = va;
            *(uint4*)(Bs + row * 32 + ch * 8) = vb;
        }
        __syncthreads();
        s16x8 rf0 = *(const s16x8*)(As + (w * 32 + 0 * 16 + l15) * 32 + g * 8);
        s16x8 rf1 = *(const s16x8*)(As + (w * 32 + 1 * 16 + l15) * 32 + g * 8);
#pragma unroll
        for (int bj = 0; bj < 8; ++bj) {
            s16x8 cf = *(const s16x8*)(Bs + (bj * 16 + l15) * 32 + g * 8);
            acc[0][bj] = __builtin_amdgcn_mfma_f32_16x16x32_bf16(cf, rf0, acc[0][bj], 0, 0, 0);
            acc[1][bj] = __builtin_amdgcn_mfma_f32_16x16x32_bf16(cf, rf1, acc[1][bj], 0, 0, 0);
        }
    }
}

__global__ __launch_bounds__(256) void k_minmax(const ushort* __restrict__ Eb,
                                                const float* __restrict__ sq,
                                                unsigned* __restrict__ mm) {
    const int rb = blockIdx.y, cb = blockIdx.x;
    if (cb < rb) return;
    __shared__ ushort As[128 * 32], Bs[128 * 32];
    __shared__ float sqr[128], sqc[128];
    __shared__ float red[8];
    const int tid = threadIdx.x;
    if (tid < 128) sqr[tid] = sq[rb * 128 + tid];
    else           sqc[tid - 128] = sq[cb * 128 + (tid - 128)];
    f32x4 acc[2][8];
#pragma unroll
    for (int bi = 0; bi < 2; ++bi)
#pragma unroll
        for (int bj = 0; bj < 8; ++bj) acc[bi][bj] = (f32x4){0.f, 0.f, 0.f, 0.f};
    gram_tile(Eb, rb, cb, As, Bs, acc);
    const int w = tid >> 6, lane = tid & 63, g = lane >> 4, l15 = lane & 15;
    const float sr0 = sqr[w * 32 + l15], sr1 = sqr[w * 32 + 16 + l15];
    float mn = 3.4e38f, mx = 0.0f;
#pragma unroll
    for (int bi = 0; bi < 2; ++bi)
#pragma unroll
        for (int bj = 0; bj < 8; ++bj)
#pragma unroll
            for (int m = 0; m < 4; ++m) {
                int tr = w * 32 + bi * 16 + l15;
                int tc = bj * 16 + g * 4 + m;
                float d2 = (bi ? sr1 : sr0) + sqc[tc] - 2.0f * acc[bi][bj][m];
                d2 = fmaxf(d2, 0.0f);
                bool diag = (rb == cb) && (tr == tc);
                mn = diag ? mn : fminf(mn, d2);
                mx = diag ? mx : fmaxf(mx, d2);
            }
#pragma unroll
    for (int s = 1; s < 64; s <<= 1) {
        mn = fminf(mn, __shfl_xor(mn, s));
        mx = fmaxf(mx, __shfl_xor(mx, s));
    }
    if (lane == 0) { red[w] = mn; red[4 + w] = mx; }
    __syncthreads();
    if (tid == 0) {
        mn = fminf(fminf(red[0], red[1]), fminf(red[2], red[3]));
        mx = fmaxf(fmaxf(red[4], red[5]), fmaxf(red[6], red[7]));
        atomicMin(&mm[0], __float_as_uint(mn));
        atomicMax(&mm[1], __float_as_uint(mx));
    }
}

__global__ __launch_bounds__(256) void k_accum2(const ushort* __restrict__ Eb,
                                                const float* __restrict__ sq,
                                                const unsigned* __restrict__ mm,
                                                float* __restrict__ deg) {
    const int rb = blockIdx.y, cb = blockIdx.x;
    __shared__ ushort As[128 * 32], Bs[128 * 32];
    __shared__ float sqr[128], sqc[128];
    __shared__ float degr[128][NF];
    const int tid = threadIdx.x;
    if (tid < 128) sqr[tid] = sq[rb * 128 + tid];
    else           sqc[tid - 128] = sq[cb * 128 + (tid - 128)];
    for (int i = tid; i < 128 * NF; i += 256) ((float*)degr)[i] = 0.0f;
    f32x4 acc[2][8];
#pragma unroll
    for (int bi = 0; bi < 2; ++bi)
#pragma unroll
        for (int bj = 0; bj < 8; ++bj) acc[bi][bj] = (f32x4){0.f, 0.f, 0.f, 0.f};
    gram_tile(Eb, rb, cb, As, Bs, acc);
    const int w = tid >> 6, lane = tid & 63, g = lane >> 4, l15 = lane & 15;

    const float dmin2 = __uint_as_float(mm[0]);
    const float dmax2 = __uint_as_float(mm[1]);
    const float d_min = dmin2 > 1e-12f ? sqrtf(dmin2) : 0.0f;
    const float d_mx  = dmax2 > 1e-12f ? sqrtf(dmax2) : 0.0f;
    const float d_max = fmaxf(d_mx, d_min + 1e-4f);
    const float stp   = (d_max - d_min) / 23.0f;
    const float S2L   = (1.0f / 0.15f) * 1.44269504f;
    const float Ds2   = stp * S2L;
    const float R     = exp2f(-Ds2);
    const float LIM   = 1073741824.0f;
    const float ECAP  = 125.0f;

    const float sr0 = sqr[w * 32 + l15], sr1 = sqr[w * 32 + 16 + l15];
    f32x4 ee[2][8];
#pragma unroll
    for (int bi = 0; bi < 2; ++bi)
#pragma unroll
        for (int bj = 0; bj < 8; ++bj)
#pragma unroll
            for (int m = 0; m < 4; ++m) {
                int tr = w * 32 + bi * 16 + l15;
                int tc = bj * 16 + g * 4 + m;
                float d2 = (bi ? sr1 : sr0) + sqc[tc] - 2.0f * acc[bi][bj][m];
                d2 = fmaxf(d2, 0.0f);
                float d = d2 > 1e-12f ? sqrtf(d2) : 0.0f;
                if (rb == cb && tr == tc) d = 1e9f;
                ee[bi][bj][m] = exp2f(fminf((d - d_min) * S2L, ECAP));
            }

#pragma unroll 1
    for (int t = 0; t < NF; ++t) {
        float rs0 = 0.0f, rs1 = 0.0f;
#pragma unroll
        for (int bj = 0; bj < 8; ++bj) {
            {
                f32x4 q = ee[0][bj];
                float A  = 1.0f + fminf(q.x, LIM), B  = 1.0f + fminf(q.y, LIM);
                float Cq = 1.0f + fminf(q.z, LIM), Dq = 1.0f + fminf(q.w, LIM);
                float sAB = A + B,  sCD = Cq + Dq;
                float pAB = A * B,  pCD = Cq * Dq;
                rs0 += (sAB * pCD + sCD * pAB) * __builtin_amdgcn_rcpf(pAB * pCD);
                ee[0][bj] = q * R;
            }
            {
                f32x4 q = ee[1][bj];
                float A  = 1.0f + fminf(q.x, LIM), B  = 1.0f + fminf(q.y, LIM);
                float Cq = 1.0f + fminf(q.z, LIM), Dq = 1.0f + fminf(q.w, LIM);
                float sAB = A + B,  sCD = Cq + Dq;
                float pAB = A * B,  pCD = Cq * Dq;
                rs1 += (sAB * pCD + sCD * pAB) * __builtin_amdgcn_rcpf(pAB * pCD);
                ee[1][bj] = q * R;
            }
        }
        rs0 += __shfl_xor(rs0, 16); rs0 += __shfl_xor(rs0, 32);
        rs1 += __shfl_xor(rs1, 16); rs1 += __shfl_xor(rs1, 32);
        if (g == 0) {
            degr[w * 32 + l15][t]      += rs0;
            degr[w * 32 + 16 + l15][t] += rs1;
        }
    }
    __syncthreads();
    for (int i = tid; i < 128 * NF; i += 256) {
        int r = i / NF, t = i % NF;
        atomicAdd(&deg[(size_t)(rb * 128 + r) * NF + t], degr[r][t]);
    }
}

__global__ __launch_bounds__(256) void k_final(const float* __restrict__ deg,
                                               float* __restrict__ out) {
    const int tid = threadIdx.x;
    float s[NF], cnt[8];
#pragma unroll
    for (int t = 0; t < NF; ++t) s[t] = 0.0f;
#pragma unroll
    for (int k = 0; k < 8; ++k) cnt[k] = 0.0f;
    for (int i = tid; i < NPTS; i += 256) {
        const float* row = deg + (size_t)i * NF;
#pragma unroll
        for (int t = 0; t < NF; ++t) {
            float v = row[t];
            s[t] += v;
            if (t >= 16) cnt[t - 16] += (v < 0.5f) ? 1.0f : 0.0f;
        }
    }
#pragma unroll
    for (int t = 0; t < NF; ++t)
#pragma unroll
        for (int o = 1; o < 64; o <<= 1) s[t] += __shfl_xor(s[t], o);
#pragma unroll
    for (int k = 0; k < 8; ++k)
#pragma unroll
        for (int o = 1; o < 64; o <<= 1) cnt[k] += __shfl_xor(cnt[k], o);
    __shared__ float red[4][32];
    const int w = tid >> 6, lane = tid & 63;
    if (lane == 0) {
#pragma unroll
        for (int t = 0; t < NF; ++t) red[w][t] = s[t];
#pragma unroll
        for (int k = 0; k < 8; ++k) red[w][NF + k] = cnt[k];
    }
    __syncthreads();
    if (tid == 0) {
        float h0 = 0.0f, h1 = 0.0f;
#pragma unroll
        for (int t = 0; t < NF; ++t) {
            float S = red[0][t] + red[1][t] + red[2][t] + red[3][t];
            float edges = S * 0.5f;
            h1 += fmaxf(edges - (float)(NPTS - 1), 0.0f) / (float)NPTS;
        }
#pragma unroll
        for (int k = 0; k < 8; ++k)
            h0 += red[0][NF + k] + red[1][NF + k] + red[2][NF + k] + red[3][NF + k];
        h0 *= (1.0f / 8.0f);
        h1 *= (1.0f / 24.0f);
        out[0] = (h0 + 0.5f * h1) * 0.1f;
    }
}

extern "C" void kernel_launch(void* const* d_in, const int* in_sizes, int n_in,
                              void* d_out, int out_size, void* d_ws, size_t ws_size,
                              hipStream_t stream) {
    (void)in_sizes; (void)n_in; (void)out_size;
    const float* emb = (const float*)d_in[0];
    uint8_t* ws = (uint8_t*)d_ws;
    ushort*   Eb  = (ushort*)(ws);
    float*    sqv = (float*)(ws + OFF_SQ);
    unsigned* mm  = (unsigned*)(ws + OFF_MM);
    float*    deg = (float*)(ws + OFF_DEG);   // path A: acc32 lives in deg[0..31]
    ushort*   D2h = (ushort*)(ws + OFF_D);
    float*    out = (float*)d_out;
    const bool bigws = (ws_size >= WS_A);

    if (bigws) {
        k_convert  <<<dim3(NPTS / 4),              dim3(256), 0, stream>>>(emb, Eb, sqv, deg, mm);
        k_gram_bk64<<<dim3(NBLK * (NBLK + 1) / 2), dim3(256), 0, stream>>>(Eb, sqv, mm, D2h);
        k_hd       <<<dim3(NPTS / 8),              dim3(512), 0, stream>>>(D2h, mm, deg, out);
    } else {
        k_init   <<<dim3(384),      dim3(256), 0, stream>>>(deg, mm);
        k_convert<<<dim3(NPTS / 4), dim3(256), 0, stream>>>(emb, Eb, sqv, deg, mm);
        k_minmax <<<dim3(32, 32),   dim3(256), 0, stream>>>(Eb, sqv, mm);
        k_accum2 <<<dim3(32, 32),   dim3(256), 0, stream>>>(Eb, sqv, mm, deg);
        k_final  <<<dim3(1),        dim3(256), 0, stream>>>(deg, out);
    }
}

// Round 16
// 74.119 us; speedup vs baseline: 1.0212x; 1.0212x over previous
//
#include <hip/hip_runtime.h>
#include <stdint.h>

typedef float f32x4 __attribute__((ext_vector_type(4)));
typedef short s16x8 __attribute__((ext_vector_type(8)));
typedef unsigned short us4 __attribute__((ext_vector_type(4)));

#define NPTS 4096
#define DDIM 512
#define NF   24
#define NBLK 32
#define NBD  1024   // histogram bins (hist/dot)

// ---------------- ws layout ----------------
// Eb @0 (4MB) | sq | mm | acc32/deg | D2h @4,603,968 (33.5MB) | H @38,158,400 (8MB)
#define OFF_SQ  4194304
#define OFF_MM  4210688
#define OFF_DEG 4210752
#define OFF_D   4603968
#define OFF_H   38158400ULL
#define WS_A    54935616ULL

typedef __attribute__((address_space(1))) void gvoid;
typedef __attribute__((address_space(3))) void svoid;
#define GLD16(gp, lp) __builtin_amdgcn_global_load_lds((gvoid*)(gp), (svoid*)(lp), 16, 0, 0)

static __device__ __forceinline__ ushort f2h(float x) {
    _Float16 h = (_Float16)x;
    return __builtin_bit_cast(unsigned short, h);
}
static __device__ __forceinline__ float h2f(ushort u) {
    return (float)__builtin_bit_cast(_Float16, u);
}

// ---------------- init (path B only) ----------------
__global__ __launch_bounds__(256) void k_init(float* __restrict__ deg,
                                              unsigned* __restrict__ mm) {
    int i = blockIdx.x * 256 + threadIdx.x;
    if (i < NPTS * NF) deg[i] = 0.0f;
    if (i == 0) { mm[0] = 0x7F7FFFFFu; mm[1] = 0u; }
}

// ------- convert f32 -> bf16 (RNE), rowwise sum of squares; + tiny init ----
__global__ __launch_bounds__(256) void k_convert(const float* __restrict__ in,
                                                 ushort* __restrict__ Eb,
                                                 float* __restrict__ sq,
                                                 float* __restrict__ acc32,
                                                 unsigned* __restrict__ mm) {
    if (blockIdx.x == 0) {
        if (threadIdx.x < 32) acc32[threadIdx.x] = 0.0f;
        else if (threadIdx.x == 32) mm[0] = 0x7F7FFFFFu;
        else if (threadIdx.x == 33) mm[1] = 0u;
    }
    const int w = threadIdx.x >> 6, lane = threadIdx.x & 63;
    const int row = blockIdx.x * 4 + w;
    const float* src = in + (size_t)row * DDIM + lane * 8;
    float4 a = ((const float4*)src)[0];
    float4 b = ((const float4*)src)[1];
    float v[8] = {a.x, a.y, a.z, a.w, b.x, b.y, b.z, b.w};
    unsigned u[8];
    float ss = 0.0f;
#pragma unroll
    for (int i = 0; i < 8; ++i) {
        ss += v[i] * v[i];
        unsigned bits = __float_as_uint(v[i]);
        u[i] = (bits + 0x7FFFu + ((bits >> 16) & 1u)) >> 16;  // RNE to bf16
    }
    uint4 pk;
    pk.x = u[0] | (u[1] << 16);
    pk.y = u[2] | (u[3] << 16);
    pk.z = u[4] | (u[5] << 16);
    pk.w = u[6] | (u[7] << 16);
    *(uint4*)(Eb + (size_t)row * DDIM + lane * 8) = pk;
#pragma unroll
    for (int s = 1; s < 64; s <<= 1) ss += __shfl_xor(ss, s);
    if (lane == 0) sq[row] = ss;
}

// ============================ PATH A ======================================
// UPPER-TRI 128x128 tiles (528 blocks, XCD-swizzled). BK=64, one barrier per
// K-step, dbuf global_load_lds staging, 8-slot chunk-XOR swizzle both-sides.
// (round-11 measured-best gram; unchanged)
__global__ __launch_bounds__(256) void k_gram_bk64(const ushort* __restrict__ Eb,
                                                   const float* __restrict__ sq,
                                                   unsigned* __restrict__ mm,
                                                   ushort* __restrict__ D2h) {
    __shared__ __align__(16) ushort SM[32768];
    __shared__ float sqr[128], sqc[128], red[8];
    char* SMb = (char*)SM;
    const int tid = threadIdx.x;
    const int w = tid >> 6, lane = tid & 63, g = lane >> 4, l15 = lane & 15;
    const int wr = w >> 1, wc = w & 1;

    int bid = (blockIdx.x & 7) * 66 + (blockIdx.x >> 3);
    int rb = 0, pre = 0;
    while (pre + (NBLK - rb) <= bid) { pre += NBLK - rb; ++rb; }
    const int cb = rb + (bid - pre);

    if (tid < 128) sqr[tid] = sq[rb * 128 + tid];
    else           sqc[tid - 128] = sq[cb * 128 + (tid - 128)];

    f32x4 acc[4][4];
#pragma unroll
    for (int i = 0; i < 4; ++i)
#pragma unroll
        for (int j = 0; j < 4; ++j) acc[i][j] = (f32x4){0.f, 0.f, 0.f, 0.f};

    const int srow_off = lane >> 3, slch = lane & 7;

#define STAGE64(buf, kk)                                                        \
    {                                                                           \
        const int k0_ = (kk) * 64;                                              \
        _Pragma("unroll")                                                       \
        for (int i_ = 0; i_ < 4; ++i_) {                                        \
            const int r_  = w * 32 + i_ * 8 + srow_off;                         \
            const int ch_ = slch ^ (r_ & 7);                                    \
            GLD16(Eb + (size_t)(rb * 128 + r_) * DDIM + k0_ + ch_ * 8,          \
                  SMb + (buf) * 16384 + (w * 32 + i_ * 8) * 128);               \
            GLD16(Eb + (size_t)(cb * 128 + r_) * DDIM + k0_ + ch_ * 8,          \
                  SMb + 32768 + (buf) * 16384 + (w * 32 + i_ * 8) * 128);       \
        }                                                                       \
    }

    STAGE64(0, 0);
    int cur = 0;
#pragma unroll 1
    for (int kk = 0; kk < 8; ++kk) {
        __syncthreads();
        if (kk < 7) STAGE64(cur ^ 1, kk + 1);
        const char* Ac = SMb + cur * 16384;
        const char* Bc = SMb + 32768 + cur * 16384;
#pragma unroll
        for (int ks = 0; ks < 2; ++ks) {
            s16x8 rf[4], cf[4];
#pragma unroll
            for (int i = 0; i < 4; ++i) {
                const int r = wr * 64 + i * 16 + l15;
                const int slot = (ks * 4 + g) ^ (r & 7);
                rf[i] = *(const s16x8*)(Ac + r * 128 + slot * 16);
            }
#pragma unroll
            for (int j = 0; j < 4; ++j) {
                const int r = wc * 64 + j * 16 + l15;
                const int slot = (ks * 4 + g) ^ (r & 7);
                cf[j] = *(const s16x8*)(Bc + r * 128 + slot * 16);
            }
#pragma unroll
            for (int i = 0; i < 4; ++i)
#pragma unroll
                for (int j = 0; j < 4; ++j)
                    acc[i][j] = __builtin_amdgcn_mfma_f32_16x16x32_bf16(
                        cf[j], rf[i], acc[i][j], 0, 0, 0);
        }
        cur ^= 1;
    }
    __syncthreads();

    ushort* T = SM;
    float mn = 3.4e38f, mx = 0.0f;
#pragma unroll
    for (int i = 0; i < 4; ++i) {
        const int lr = wr * 64 + i * 16 + l15;
        const int trow = rb * 128 + lr;
        const float srv = sqr[lr];
#pragma unroll
        for (int j = 0; j < 4; ++j) {
            const int c0 = wc * 64 + j * 16 + g * 4;
            const int tc0 = cb * 128 + c0;
            ushort h[4];
#pragma unroll
            for (int m = 0; m < 4; ++m) {
                float d2 = srv + sqc[c0 + m] - 2.0f * acc[i][j][m];
                d2 = fmaxf(d2, 0.0f);
                bool diag = (tc0 + m == trow);
                mn = diag ? mn : fminf(mn, d2);
                mx = diag ? mx : fmaxf(mx, d2);
                h[m] = f2h(diag ? 6.0e4f : d2);   // diag -> huge d2 -> sigma == 0
            }
            us4 pk4 = {h[0], h[1], h[2], h[3]};
            *(us4*)(T + lr * 136 + c0) = pk4;
        }
    }
#pragma unroll
    for (int s = 1; s < 64; s <<= 1) {
        mn = fminf(mn, __shfl_xor(mn, s));
        mx = fmaxf(mx, __shfl_xor(mx, s));
    }
    if (lane == 0) { red[w] = mn; red[4 + w] = mx; }
    __syncthreads();
    if (tid == 0) {
        mn = fminf(fminf(red[0], red[1]), fminf(red[2], red[3]));
        mx = fmaxf(fmaxf(red[4], red[5]), fmaxf(red[6], red[7]));
        atomicMin(&mm[0], __float_as_uint(mn));
        atomicMax(&mm[1], __float_as_uint(mx));
    }
#pragma unroll
    for (int j = 0; j < 8; ++j) {
        const int c = j * 256 + tid;
        const int row = c >> 4, col8 = (c & 15) * 8;
        uint4 v = *(const uint4*)(T + row * 136 + col8);
        *(uint4*)(D2h + (size_t)(rb * 128 + row) * NPTS + cb * 128 + col8) = v;
    }
    if (rb != cb) {
        __syncthreads();
#pragma unroll
        for (int i = 0; i < 4; ++i) {
            const int lr = wr * 64 + i * 16 + l15;
            const float srv = sqr[lr];
#pragma unroll
            for (int j = 0; j < 4; ++j) {
                const int c0 = wc * 64 + j * 16 + g * 4;
#pragma unroll
                for (int m = 0; m < 4; ++m) {
                    float d2 = srv + sqc[c0 + m] - 2.0f * acc[i][j][m];
                    d2 = fmaxf(d2, 0.0f);
                    T[(c0 + m) * 136 + lr] = f2h(d2);
                }
            }
        }
        __syncthreads();
#pragma unroll
        for (int j2 = 0; j2 < 8; ++j2) {
            const int c = j2 * 256 + tid;
            const int row = c >> 4, col8 = (c & 15) * 8;
            uint4 v = *(const uint4*)(T + row * 136 + col8);
            *(uint4*)(D2h + (size_t)(cb * 128 + row) * NPTS + rb * 128 + col8) = v;
        }
    }
}

// per-row histogram (NBD bins): 4 rows/block, one wave per row, u32 LDS hist.
__global__ __launch_bounds__(256) void k_hist4(const ushort* __restrict__ D2h,
                                               const unsigned* __restrict__ mm,
                                               ushort* __restrict__ H) {
    __shared__ unsigned Hs[4][NBD + 4];
    const int tid = threadIdx.x, w = tid >> 6, lane = tid & 63;
    const int row0 = blockIdx.x * 4;
    const int row = row0 + w;
    for (int i = tid; i < 4 * (NBD + 4); i += 256) ((unsigned*)Hs)[i] = 0u;
    const float d2min = __uint_as_float(mm[0]);
    const float d2max = __uint_as_float(mm[1]);
    const float sc = (float)NBD / fmaxf(d2max - d2min, 1e-6f);
    __syncthreads();
    const uint4* Dv = (const uint4*)(D2h + (size_t)row * NPTS);
    unsigned* hr = Hs[w];
#pragma unroll
    for (int it = 0; it < 8; ++it) {
        uint4 pk = Dv[it * 64 + lane];
        unsigned pw[4] = {pk.x, pk.y, pk.z, pk.w};
#pragma unroll
        for (int i = 0; i < 4; ++i) {
            float a = h2f((ushort)(pw[i] & 0xFFFFu));
            float b = h2f((ushort)(pw[i] >> 16));
            if (a < 3.0e4f) {   // excludes the diagonal marker (6e4)
                int ba = (int)fminf(fmaxf((a - d2min) * sc, 0.0f), (float)(NBD - 1));
                atomicAdd(&hr[ba], 1u);
            }
            if (b < 3.0e4f) {
                int bb = (int)fminf(fmaxf((b - d2min) * sc, 0.0f), (float)(NBD - 1));
                atomicAdd(&hr[bb], 1u);
            }
        }
    }
    __syncthreads();
    unsigned* Ho = (unsigned*)(H + (size_t)row0 * NBD);
    for (int i = tid; i < 4 * (NBD / 2); i += 256) {
        const int r = i >> 9, pw_ = i & 511;
        unsigned lo = Hs[r][2 * pw_], hi = Hs[r][2 * pw_ + 1];
        Ho[r * (NBD / 2) + pw_] = (lo & 0xFFFFu) | (hi << 16);
    }
}

// deg[row][k] = sum_b hist[row][b] * sigma((t_k - d_b)/T); W generated in LDS.
// One wave per row, 8 rows per block; block-level finalize into acc32.
__global__ __launch_bounds__(512) void k_dot(const ushort* __restrict__ H,
                                             const unsigned* __restrict__ mm,
                                             float* __restrict__ acc32) {
    __shared__ float Wl[4][NBD];   // 16KB
    __shared__ float degb[8][NF];
    const int tid = threadIdx.x;
    const int wid = tid >> 6, lane = tid & 63;
    const int row = blockIdx.x * 8 + wid;

    const float d2min = __uint_as_float(mm[0]);
    const float d2max = __uint_as_float(mm[1]);
    const float bw    = fmaxf(d2max - d2min, 1e-6f) / (float)NBD;
    const float d_min = d2min > 1e-12f ? sqrtf(d2min) : 0.0f;
    const float d_mx  = d2max > 1e-12f ? sqrtf(d2max) : 0.0f;
    const float d_max = fmaxf(d_mx, d_min + 1e-4f);
    const float stp   = (d_max - d_min) / 23.0f;
    const float S2L   = (1.0f / 0.15f) * 1.44269504f;
    const float Ds2   = stp * S2L;
    const float R     = exp2f(-Ds2);
    const float LIM   = 1073741824.0f;

    // hv: lane owns bins j*256 + lane*4 (j = 0..3) -> 16 bins
    float hv[16];
    const ushort* Hr = H + (size_t)row * NBD;
#pragma unroll
    for (int j = 0; j < 4; ++j) {
        uint2 pk = *(const uint2*)(Hr + j * 256 + lane * 4);
        hv[j * 4 + 0] = (float)(pk.x & 0xFFFFu);
        hv[j * 4 + 1] = (float)(pk.x >> 16);
        hv[j * 4 + 2] = (float)(pk.y & 0xFFFFu);
        hv[j * 4 + 3] = (float)(pk.y >> 16);
    }

    // W-gen state: thread owns bins tid*2+q (512 threads x 2 = 1024)
    float e2[2];
#pragma unroll
    for (int q = 0; q < 2; ++q) {
        const int b = tid * 2 + q;
        const float d2c = d2min + ((float)b + 0.5f) * bw;
        const float db = sqrtf(fmaxf(d2c, 0.0f));
        e2[q] = exp2f(fminf((db - d_min) * S2L, 125.0f));
    }

#pragma unroll 1
    for (int ph = 0; ph < 6; ++ph) {
        __syncthreads();   // previous phase's readers done before overwrite
#pragma unroll
        for (int k = 0; k < 4; ++k) {
            float2 sg;
            sg.x = __builtin_amdgcn_rcpf(1.0f + fminf(e2[0], LIM)); e2[0] *= R;
            sg.y = __builtin_amdgcn_rcpf(1.0f + fminf(e2[1], LIM)); e2[1] *= R;
            *(float2*)(&Wl[k][tid * 2]) = sg;
        }
        __syncthreads();
        float dacc[4];
#pragma unroll
        for (int k = 0; k < 4; ++k) {
            const float* Wr = &Wl[k][0];
            float s = 0.0f;
#pragma unroll
            for (int j = 0; j < 4; ++j) {
                const f32x4 wv = *(const f32x4*)(Wr + j * 256 + lane * 4);
                s += hv[j*4+0]*wv[0] + hv[j*4+1]*wv[1] + hv[j*4+2]*wv[2] + hv[j*4+3]*wv[3];
            }
            dacc[k] = s;
        }
#pragma unroll
        for (int k = 0; k < 4; ++k)
#pragma unroll
            for (int o = 1; o < 64; o <<= 1) dacc[k] += __shfl_xor(dacc[k], o);
        if (lane == 0) {
#pragma unroll
            for (int k = 0; k < 4; ++k) degb[wid][ph * 4 + k] = dacc[k];
        }
    }
    __syncthreads();
    if (tid < NF) {            // edge sums
        float s = 0.0f;
#pragma unroll
        for (int r = 0; r < 8; ++r) s += degb[r][tid];
        atomicAdd(&acc32[tid], s);
    } else if (tid < 32) {     // isolated counts over thresholds 16..23
        const int k = 16 + (tid - NF);
        float c = 0.0f;
#pragma unroll
        for (int r = 0; r < 8; ++r) c += (degb[r][k] < 0.5f) ? 1.0f : 0.0f;
        atomicAdd(&acc32[tid], c);
    }
}

// tiny finalize for path A
__global__ __launch_bounds__(64) void k_final2(const float* __restrict__ acc32,
                                               float* __restrict__ out) {
    if (threadIdx.x == 0) {
        float h1 = 0.0f;
#pragma unroll
        for (int k = 0; k < NF; ++k)
            h1 += fmaxf(acc32[k] * 0.5f - (float)(NPTS - 1), 0.0f) * (1.0f / (float)NPTS);
        float h0 = 0.0f;
#pragma unroll
        for (int k = 0; k < 8; ++k) h0 += acc32[NF + k];
        out[0] = (h0 * 0.125f + 0.5f * (h1 * (1.0f / 24.0f))) * 0.1f;
    }
}

// ============================ PATH B (small ws, verified) ==================
__device__ __forceinline__ void gram_tile(const ushort* __restrict__ Eb, int rb, int cb,
                                          ushort* As, ushort* Bs, f32x4 acc[2][8]) {
    const int tid = threadIdx.x;
    const int w = tid >> 6, lane = tid & 63, g = lane >> 4, l15 = lane & 15;
#pragma unroll 1
    for (int kk = 0; kk < DDIM / 32; ++kk) {
        const int k0 = kk * 32;
        __syncthreads();
#pragma unroll
        for (int it = 0; it < 2; ++it) {
            int li  = it * 256 + tid;
            int row = li >> 2, ch = li & 3;
            uint4 va = *(const uint4*)(Eb + (size_t)(rb * 128 + row) * DDIM + k0 + ch * 8);
            uint4 vb = *(const uint4*)(Eb + (size_t)(cb * 128 + row) * DDIM + k0 + ch * 8);
            *(uint4*)(As + row * 32 + ch * 8) = va;
            *(uint4*)(Bs + row * 32 + ch * 8) = vb;
        }
        __syncthreads();
        s16x8 rf0 = *(const s16x8*)(As + (w * 32 + 0 * 16 + l15) * 32 + g * 8);
        s16x8 rf1 = *(const s16x8*)(As + (w * 32 + 1 * 16 + l15) * 32 + g * 8);
#pragma unroll
        for (int bj = 0; bj < 8; ++bj) {
            s16x8 cf = *(const s16x8*)(Bs + (bj * 16 + l15) * 32 + g * 8);
            acc[0][bj] = __builtin_amdgcn_mfma_f32_16x16x32_bf16(cf, rf0, acc[0][bj], 0, 0, 0);
            acc[1][bj] = __builtin_amdgcn_mfma_f32_16x16x32_bf16(cf, rf1, acc[1][bj], 0, 0, 0);
        }
    }
}

__global__ __launch_bounds__(256) void k_minmax(const ushort* __restrict__ Eb,
                                                const float* __restrict__ sq,
                                                unsigned* __restrict__ mm) {
    const int rb = blockIdx.y, cb = blockIdx.x;
    if (cb < rb) return;
    __shared__ ushort As[128 * 32], Bs[128 * 32];
    __shared__ float sqr[128], sqc[128];
    __shared__ float red[8];
    const int tid = threadIdx.x;
    if (tid < 128) sqr[tid] = sq[rb * 128 + tid];
    else           sqc[tid - 128] = sq[cb * 128 + (tid - 128)];
    f32x4 acc[2][8];
#pragma unroll
    for (int bi = 0; bi < 2; ++bi)
#pragma unroll
        for (int bj = 0; bj < 8; ++bj) acc[bi][bj] = (f32x4){0.f, 0.f, 0.f, 0.f};
    gram_tile(Eb, rb, cb, As, Bs, acc);
    const int w = tid >> 6, lane = tid & 63, g = lane >> 4, l15 = lane & 15;
    const float sr0 = sqr[w * 32 + l15], sr1 = sqr[w * 32 + 16 + l15];
    float mn = 3.4e38f, mx = 0.0f;
#pragma unroll
    for (int bi = 0; bi < 2; ++bi)
#pragma unroll
        for (int bj = 0; bj < 8; ++bj)
#pragma unroll
            for (int m = 0; m < 4; ++m) {
                int tr = w * 32 + bi * 16 + l15;
                int tc = bj * 16 + g * 4 + m;
                float d2 = (bi ? sr1 : sr0) + sqc[tc] - 2.0f * acc[bi][bj][m];
                d2 = fmaxf(d2, 0.0f);
                bool diag = (rb == cb) && (tr == tc);
                mn = diag ? mn : fminf(mn, d2);
                mx = diag ? mx : fmaxf(mx, d2);
            }
#pragma unroll
    for (int s = 1; s < 64; s <<= 1) {
        mn = fminf(mn, __shfl_xor(mn, s));
        mx = fmaxf(mx, __shfl_xor(mx, s));
    }
    if (lane == 0) { red[w] = mn; red[4 + w] = mx; }
    __syncthreads();
    if (tid == 0) {
        mn = fminf(fminf(red[0], red[1]), fminf(red[2], red[3]));
        mx = fmaxf(fmaxf(red[4], red[5]), fmaxf(red[6], red[7]));
        atomicMin(&mm[0], __float_as_uint(mn));
        atomicMax(&mm[1], __float_as_uint(mx));
    }
}

__global__ __launch_bounds__(256) void k_accum2(const ushort* __restrict__ Eb,
                                                const float* __restrict__ sq,
                                                const unsigned* __restrict__ mm,
                                                float* __restrict__ deg) {
    const int rb = blockIdx.y, cb = blockIdx.x;
    __shared__ ushort As[128 * 32], Bs[128 * 32];
    __shared__ float sqr[128], sqc[128];
    __shared__ float degr[128][NF];
    const int tid = threadIdx.x;
    if (tid < 128) sqr[tid] = sq[rb * 128 + tid];
    else           sqc[tid - 128] = sq[cb * 128 + (tid - 128)];
    for (int i = tid; i < 128 * NF; i += 256) ((float*)degr)[i] = 0.0f;
    f32x4 acc[2][8];
#pragma unroll
    for (int bi = 0; bi < 2; ++bi)
#pragma unroll
        for (int bj = 0; bj < 8; ++bj) acc[bi][bj] = (f32x4){0.f, 0.f, 0.f, 0.f};
    gram_tile(Eb, rb, cb, As, Bs, acc);
    const int w = tid >> 6, lane = tid & 63, g = lane >> 4, l15 = lane & 15;

    const float dmin2 = __uint_as_float(mm[0]);
    const float dmax2 = __uint_as_float(mm[1]);
    const float d_min = dmin2 > 1e-12f ? sqrtf(dmin2) : 0.0f;
    const float d_mx  = dmax2 > 1e-12f ? sqrtf(dmax2) : 0.0f;
    const float d_max = fmaxf(d_mx, d_min + 1e-4f);
    const float stp   = (d_max - d_min) / 23.0f;
    const float S2L   = (1.0f / 0.15f) * 1.44269504f;
    const float Ds2   = stp * S2L;
    const float R     = exp2f(-Ds2);
    const float LIM   = 1073741824.0f;
    const float ECAP  = 125.0f;

    const float sr0 = sqr[w * 32 + l15], sr1 = sqr[w * 32 + 16 + l15];
    f32x4 ee[2][8];
#pragma unroll
    for (int bi = 0; bi < 2; ++bi)
#pragma unroll
        for (int bj = 0; bj < 8; ++bj)
#pragma unroll
            for (int m = 0; m < 4; ++m) {
                int tr = w * 32 + bi * 16 + l15;
                int tc = bj * 16 + g * 4 + m;
                float d2 = (bi ? sr1 : sr0) + sqc[tc] - 2.0f * acc[bi][bj][m];
                d2 = fmaxf(d2, 0.0f);
                float d = d2 > 1e-12f ? sqrtf(d2) : 0.0f;
                if (rb == cb && tr == tc) d = 1e9f;
                ee[bi][bj][m] = exp2f(fminf((d - d_min) * S2L, ECAP));
            }

#pragma unroll 1
    for (int t = 0; t < NF; ++t) {
        float rs0 = 0.0f, rs1 = 0.0f;
#pragma unroll
        for (int bj = 0; bj < 8; ++bj) {
            {
                f32x4 q = ee[0][bj];
                float A  = 1.0f + fminf(q.x, LIM), B  = 1.0f + fminf(q.y, LIM);
                float Cq = 1.0f + fminf(q.z, LIM), Dq = 1.0f + fminf(q.w, LIM);
                float sAB = A + B,  sCD = Cq + Dq;
                float pAB = A * B,  pCD = Cq * Dq;
                rs0 += (sAB * pCD + sCD * pAB) * __builtin_amdgcn_rcpf(pAB * pCD);
                ee[0][bj] = q * R;
            }
            {
                f32x4 q = ee[1][bj];
                float A  = 1.0f + fminf(q.x, LIM), B  = 1.0f + fminf(q.y, LIM);
                float Cq = 1.0f + fminf(q.z, LIM), Dq = 1.0f + fminf(q.w, LIM);
                float sAB = A + B,  sCD = Cq + Dq;
                float pAB = A * B,  pCD = Cq * Dq;
                rs1 += (sAB * pCD + sCD * pAB) * __builtin_amdgcn_rcpf(pAB * pCD);
                ee[1][bj] = q * R;
            }
        }
        rs0 += __shfl_xor(rs0, 16); rs0 += __shfl_xor(rs0, 32);
        rs1 += __shfl_xor(rs1, 16); rs1 += __shfl_xor(rs1, 32);
        if (g == 0) {
            degr[w * 32 + l15][t]      += rs0;
            degr[w * 32 + 16 + l15][t] += rs1;
        }
    }
    __syncthreads();
    for (int i = tid; i < 128 * NF; i += 256) {
        int r = i / NF, t = i % NF;
        atomicAdd(&deg[(size_t)(rb * 128 + r) * NF + t], degr[r][t]);
    }
}

__global__ __launch_bounds__(256) void k_final(const float* __restrict__ deg,
                                               float* __restrict__ out) {
    const int tid = threadIdx.x;
    float s[NF], cnt[8];
#pragma unroll
    for (int t = 0; t < NF; ++t) s[t] = 0.0f;
#pragma unroll
    for (int k = 0; k < 8; ++k) cnt[k] = 0.0f;
    for (int i = tid; i < NPTS; i += 256) {
        const float* row = deg + (size_t)i * NF;
#pragma unroll
        for (int t = 0; t < NF; ++t) {
            float v = row[t];
            s[t] += v;
            if (t >= 16) cnt[t - 16] += (v < 0.5f) ? 1.0f : 0.0f;
        }
    }
#pragma unroll
    for (int t = 0; t < NF; ++t)
#pragma unroll
        for (int o = 1; o < 64; o <<= 1) s[t] += __shfl_xor(s[t], o);
#pragma unroll
    for (int k = 0; k < 8; ++k)
#pragma unroll
        for (int o = 1; o < 64; o <<= 1) cnt[k] += __shfl_xor(cnt[k], o);
    __shared__ float red[4][32];
    const int w = tid >> 6, lane = tid & 63;
    if (lane == 0) {
#pragma unroll
        for (int t = 0; t < NF; ++t) red[w][t] = s[t];
#pragma unroll
        for (int k = 0; k < 8; ++k) red[w][NF + k] = cnt[k];
    }
    __syncthreads();
    if (tid == 0) {
        float h0 = 0.0f, h1 = 0.0f;
#pragma unroll
        for (int t = 0; t < NF; ++t) {
            float S = red[0][t] + red[1][t] + red[2][t] + red[3][t];
            float edges = S * 0.5f;
            h1 += fmaxf(edges - (float)(NPTS - 1), 0.0f) / (float)NPTS;
        }
#pragma unroll
        for (int k = 0; k < 8; ++k)
            h0 += red[0][NF + k] + red[1][NF + k] + red[2][NF + k] + red[3][NF + k];
        h0 *= (1.0f / 8.0f);
        h1 *= (1.0f / 24.0f);
        out[0] = (h0 + 0.5f * h1) * 0.1f;
    }
}

extern "C" void kernel_launch(void* const* d_in, const int* in_sizes, int n_in,
                              void* d_out, int out_size, void* d_ws, size_t ws_size,
                              hipStream_t stream) {
    (void)in_sizes; (void)n_in; (void)out_size;
    const float* emb = (const float*)d_in[0];
    uint8_t* ws = (uint8_t*)d_ws;
    ushort*   Eb  = (ushort*)(ws);
    float*    sqv = (float*)(ws + OFF_SQ);
    unsigned* mm  = (unsigned*)(ws + OFF_MM);
    float*    deg = (float*)(ws + OFF_DEG);   // path A: acc32 lives in deg[0..31]
    ushort*   D2h = (ushort*)(ws + OFF_D);
    ushort*   H   = (ushort*)(ws + OFF_H);
    float*    out = (float*)d_out;
    const bool bigws = (ws_size >= WS_A);

    if (bigws) {
        k_convert  <<<dim3(NPTS / 4),              dim3(256), 0, stream>>>(emb, Eb, sqv, deg, mm);
        k_gram_bk64<<<dim3(NBLK * (NBLK + 1) / 2), dim3(256), 0, stream>>>(Eb, sqv, mm, D2h);
        k_hist4    <<<dim3(NPTS / 4),              dim3(256), 0, stream>>>(D2h, mm, H);
        k_dot      <<<dim3(NPTS / 8),              dim3(512), 0, stream>>>(H, mm, deg);
        k_final2   <<<dim3(1),                     dim3(64),  0, stream>>>(deg, out);
    } else {
        k_init   <<<dim3(384),      dim3(256), 0, stream>>>(deg, mm);
        k_convert<<<dim3(NPTS / 4), dim3(256), 0, stream>>>(emb, Eb, sqv, deg, mm);
        k_minmax <<<dim3(32, 32),   dim3(256), 0, stream>>>(Eb, sqv, mm);
        k_accum2 <<<dim3(32, 32),   dim3(256), 0, stream>>>(Eb, sqv, mm, deg);
        k_final  <<<dim3(1),        dim3(256), 0, stream>>>(deg, out);
    }
}